// Round 1
// baseline (1016.736 us; speedup 1.0000x reference)
//
#include <hip/hip_runtime.h>
#include <math.h>

#define FIN 256      // input features
#define F1  32       // heads1 * C1
#define H1  2
#define C1  16
#define C2  40       // layer-2 out channels (= num classes)
#define MAXDEG 96    // padded adjacency capacity (Poisson(32) tail ~1e-18/node)
#define NEG_SLOPE 0.2f
#define GAT_EPS 1e-16f
#define G1_NODES 32  // nodes per block in GEMM1

__device__ __forceinline__ float lrelu(float v) { return v >= 0.f ? v : NEG_SLOPE * v; }

// ---------------- K1: build padded adjacency (incoming edges per dst) ----------
__global__ void k_fill_adj(const int* __restrict__ ei, int E, int N,
                           int* __restrict__ deg, int* __restrict__ adj) {
    int j = blockIdx.x * blockDim.x + threadIdx.x;
    int total = E + N;
    if (j >= total) return;
    int s, d;
    if (j < E) { s = ei[j]; d = ei[E + j]; }     // edge_index[0][j], edge_index[1][j]
    else       { s = j - E; d = s; }             // self loop
    int pos = atomicAdd(&deg[d], 1);
    if (pos < MAXDEG) adj[d * MAXDEG + pos] = s;
}

// ---------------- K2: h1 = x @ W1  [N,256]@[256,32] ---------------------------
__global__ __launch_bounds__(256) void k_gemm1(const float* __restrict__ x,
                                               const float* __restrict__ W1,
                                               float* __restrict__ h1, int N) {
    __shared__ float xs[G1_NODES * FIN];   // 32 KB
    __shared__ float Ws[FIN * F1];         // 32 KB
    int tid = threadIdx.x;
    int node0 = blockIdx.x * G1_NODES;

    const float4* W4 = (const float4*)W1;
    float4* Ws4 = (float4*)Ws;
    for (int i = tid; i < FIN * F1 / 4; i += 256) Ws4[i] = W4[i];

    const float4* x4 = (const float4*)x;
    float4* xs4 = (float4*)xs;
    for (int i = tid; i < G1_NODES * FIN / 4; i += 256) {
        int r = i >> 6;                    // 64 float4 per row
        int n = node0 + r;
        float4 v = make_float4(0.f, 0.f, 0.f, 0.f);
        if (n < N) v = x4[(size_t)n * 64 + (i & 63)];
        xs4[i] = v;
    }
    __syncthreads();

    int ln = tid >> 3;                     // local node 0..31
    int c0 = (tid & 7) * 4;                // output col group
    float a0 = 0.f, a1 = 0.f, a2 = 0.f, a3 = 0.f;
    for (int k = 0; k < FIN; k += 4) {
        float4 xv = *(const float4*)&xs[ln * FIN + k];
        float4 w0 = *(const float4*)&Ws[(k + 0) * F1 + c0];
        float4 w1 = *(const float4*)&Ws[(k + 1) * F1 + c0];
        float4 w2 = *(const float4*)&Ws[(k + 2) * F1 + c0];
        float4 w3 = *(const float4*)&Ws[(k + 3) * F1 + c0];
        a0 += xv.x * w0.x + xv.y * w1.x + xv.z * w2.x + xv.w * w3.x;
        a1 += xv.x * w0.y + xv.y * w1.y + xv.z * w2.y + xv.w * w3.y;
        a2 += xv.x * w0.z + xv.y * w1.z + xv.z * w2.z + xv.w * w3.z;
        a3 += xv.x * w0.w + xv.y * w1.w + xv.z * w2.w + xv.w * w3.w;
    }
    int n = node0 + ln;
    if (n < N) {
        float4 o = make_float4(a0, a1, a2, a3);
        *(float4*)&h1[(size_t)n * F1 + c0] = o;
    }
}

// ---------------- K3: per-node attention dots, layer 1 -------------------------
__global__ void k_attdots1(const float* __restrict__ h1,
                           const float* __restrict__ attS, const float* __restrict__ attD,
                           float* __restrict__ aS, float* __restrict__ aD, int N) {
    int idx = blockIdx.x * blockDim.x + threadIdx.x;
    if (idx >= N * H1) return;
    int n = idx >> 1, h = idx & 1;
    const float* hp = h1 + (size_t)n * F1 + h * C1;
    const float* sp = attS + h * C1;
    const float* dp = attD + h * C1;
    float s = 0.f, d = 0.f;
#pragma unroll
    for (int c = 0; c < C1; c++) { float v = hp[c]; s += v * sp[c]; d += v * dp[c]; }
    aS[idx] = s; aD[idx] = d;
}

// ---------------- K4: layer-1 softmax-aggregate (one wave per node) ------------
__global__ __launch_bounds__(256) void k_agg1(const float* __restrict__ h1,
                                              const int* __restrict__ adj,
                                              const int* __restrict__ deg,
                                              const float* __restrict__ aS,
                                              const float* __restrict__ aD,
                                              const float* __restrict__ b1,
                                              float* __restrict__ h1r, int N) {
    int warp = threadIdx.x >> 6;
    int lane = threadIdx.x & 63;
    int node = blockIdx.x * 4 + warp;
    if (node >= N) return;
    int dg = min(deg[node], MAXDEG);
    float2 adp = *(const float2*)&aD[node * 2];
    const int* ap = adj + (size_t)node * MAXDEG;

    // phase 1: per-head max over incoming edges
    float m0 = -INFINITY, m1 = -INFINITY;
    for (int j = lane; j < dg; j += 64) {
        int s = ap[j];
        float2 as = *(const float2*)&aS[2 * s];
        m0 = fmaxf(m0, lrelu(as.x + adp.x));
        m1 = fmaxf(m1, lrelu(as.y + adp.y));
    }
#pragma unroll
    for (int off = 32; off; off >>= 1) {
        m0 = fmaxf(m0, __shfl_xor(m0, off));
        m1 = fmaxf(m1, __shfl_xor(m1, off));
    }

    // phase 2: 2 edge-groups x 32 channels
    int g = lane >> 5;
    int c = lane & 31;
    int head = c >> 4;
    float mh  = head ? m1 : m0;
    float adh = head ? adp.y : adp.x;
    float acc = 0.f, sw = 0.f;
    for (int j = g; j < dg; j += 2) {
        int s = ap[j];
        float e = lrelu(aS[2 * s + head] + adh);
        float w = __expf(e - mh);
        sw  += w;
        acc += w * h1[(size_t)s * F1 + c];
    }
    acc += __shfl_xor(acc, 32);
    sw  += __shfl_xor(sw, 32);
    float out = acc / (sw + GAT_EPS) + b1[c];
    out = fmaxf(out, 0.f);                 // ReLU between layers
    if (lane < 32) h1r[(size_t)node * F1 + c] = out;
}

// ---------------- K5: h2 = h1r @ W2  [N,32]@[32,40] ---------------------------
__global__ __launch_bounds__(320) void k_gemm2(const float* __restrict__ h1r,
                                               const float* __restrict__ W2,
                                               float* __restrict__ h2, int N) {
    __shared__ float hs[8 * F1];       // 1 KB
    __shared__ float Ws[F1 * C2];      // 5 KB
    int tid = threadIdx.x;
    int node0 = blockIdx.x * 8;
    for (int i = tid; i < F1 * C2; i += 320) Ws[i] = W2[i];
    if (tid < 8 * F1) {
        int r = tid >> 5;
        int n = node0 + r;
        hs[tid] = (n < N) ? h1r[(size_t)n * F1 + (tid & 31)] : 0.f;
    }
    __syncthreads();
    int node = tid / C2;
    int col  = tid - node * C2;        // 320 = 8 * 40 exactly
    int n = node0 + node;
    if (n < N) {
        float acc = 0.f;
#pragma unroll
        for (int k = 0; k < F1; k++) acc += hs[node * F1 + k] * Ws[k * C2 + col];
        h2[(size_t)n * C2 + col] = acc;
    }
}

// ---------------- K6: per-node attention dots, layer 2 -------------------------
__global__ void k_attdots2(const float* __restrict__ h2,
                           const float* __restrict__ attS, const float* __restrict__ attD,
                           float* __restrict__ aS, float* __restrict__ aD, int N) {
    int n = blockIdx.x * blockDim.x + threadIdx.x;
    if (n >= N) return;
    const float* hp = h2 + (size_t)n * C2;
    float s = 0.f, d = 0.f;
#pragma unroll
    for (int c = 0; c < C2; c++) { float v = hp[c]; s += v * attS[c]; d += v * attD[c]; }
    aS[n] = s; aD[n] = d;
}

// ---------------- K7: layer-2 aggregate + bias + log_softmax -------------------
__global__ __launch_bounds__(256) void k_agg2(const float* __restrict__ h2,
                                              const int* __restrict__ adj,
                                              const int* __restrict__ deg,
                                              const float* __restrict__ aS,
                                              const float* __restrict__ aD,
                                              const float* __restrict__ b2,
                                              float* __restrict__ out, int N) {
    int warp = threadIdx.x >> 6;
    int lane = threadIdx.x & 63;
    int node = blockIdx.x * 4 + warp;
    if (node >= N) return;
    int dg = min(deg[node], MAXDEG);
    float ad = aD[node];
    const int* ap = adj + (size_t)node * MAXDEG;

    float m = -INFINITY;
    for (int j = lane; j < dg; j += 64)
        m = fmaxf(m, lrelu(aS[ap[j]] + ad));
#pragma unroll
    for (int off = 32; off; off >>= 1) m = fmaxf(m, __shfl_xor(m, off));

    bool act = lane < C2;
    float acc = 0.f, sw = 0.f;
    for (int j = 0; j < dg; j++) {
        int s = ap[j];
        float w = __expf(lrelu(aS[s] + ad) - m);
        sw += w;
        if (act) acc += w * h2[(size_t)s * C2 + lane];
    }
    float val = -INFINITY;
    if (act) val = acc / (sw + GAT_EPS) + b2[lane];

    // log_softmax over the 40 class lanes
    float lm = val;
#pragma unroll
    for (int off = 32; off; off >>= 1) lm = fmaxf(lm, __shfl_xor(lm, off));
    float ex = act ? __expf(val - lm) : 0.f;
#pragma unroll
    for (int off = 32; off; off >>= 1) ex += __shfl_xor(ex, off);
    if (act) out[(size_t)node * C2 + lane] = val - lm - __logf(ex);
}

extern "C" void kernel_launch(void* const* d_in, const int* in_sizes, int n_in,
                              void* d_out, int out_size, void* d_ws, size_t ws_size,
                              hipStream_t stream) {
    const float* x    = (const float*)d_in[0];
    const int*   ei   = (const int*)d_in[1];
    const float* W1   = (const float*)d_in[2];
    const float* aS1w = (const float*)d_in[3];
    const float* aD1w = (const float*)d_in[4];
    const float* b1   = (const float*)d_in[5];
    const float* W2   = (const float*)d_in[6];
    const float* aS2w = (const float*)d_in[7];
    const float* aD2w = (const float*)d_in[8];
    const float* b2   = (const float*)d_in[9];
    const int N = in_sizes[0] / FIN;
    const int E = in_sizes[1] / 2;

    char* ws = (char*)d_ws;
    size_t off = 0;
    auto alloc = [&](size_t bytes) -> void* {
        void* p = ws + off;
        off = (off + bytes + 511) & ~(size_t)511;
        return p;
    };
    int*   deg = (int*)alloc(sizeof(int) * (size_t)N);
    int*   adj = (int*)alloc(sizeof(int) * (size_t)N * MAXDEG);
    float* h1  = (float*)alloc(sizeof(float) * (size_t)N * F1);
    float* aS1 = (float*)alloc(sizeof(float) * (size_t)N * H1);
    float* aD1 = (float*)alloc(sizeof(float) * (size_t)N * H1);
    float* h1r = (float*)alloc(sizeof(float) * (size_t)N * F1);
    float* h2  = (float*)alloc(sizeof(float) * (size_t)N * C2);
    float* aS2 = (float*)alloc(sizeof(float) * (size_t)N);
    float* aD2 = (float*)alloc(sizeof(float) * (size_t)N);

    hipMemsetAsync(deg, 0, sizeof(int) * (size_t)N, stream);
    int total = E + N;
    k_fill_adj<<<(total + 255) / 256, 256, 0, stream>>>(ei, E, N, deg, adj);
    k_gemm1<<<(N + G1_NODES - 1) / G1_NODES, 256, 0, stream>>>(x, W1, h1, N);
    k_attdots1<<<(N * H1 + 255) / 256, 256, 0, stream>>>(h1, aS1w, aD1w, aS1, aD1, N);
    k_agg1<<<(N + 3) / 4, 256, 0, stream>>>(h1, adj, deg, aS1, aD1, b1, h1r, N);
    k_gemm2<<<(N + 7) / 8, 320, 0, stream>>>(h1r, W2, h2, N);
    k_attdots2<<<(N + 255) / 256, 256, 0, stream>>>(h2, aS2w, aD2w, aS2, aD2, N);
    k_agg2<<<(N + 3) / 4, 256, 0, stream>>>(h2, adj, deg, aS2, aD2, b2, (float*)d_out, N);
}

// Round 3
// 595.339 us; speedup vs baseline: 1.7078x; 1.7078x over previous
//
#include <hip/hip_runtime.h>
#include <math.h>

#define FIN 256      // input features
#define F1  32       // heads1 * C1
#define H1  2
#define C1  16
#define C2  40       // layer-2 out channels (= num classes)
#define MAXDEG 96    // padded adjacency capacity (Poisson(32) tail ~1e-18/node)
#define NEG_SLOPE 0.2f
#define GAT_EPS 1e-16f
#define G1_NODES 32  // nodes per block in GEMM1

__device__ __forceinline__ float lrelu(float v) { return v >= 0.f ? v : NEG_SLOPE * v; }

// ---------------- K1: build padded adjacency (incoming edges per dst) ----------
__global__ void k_fill_adj(const int* __restrict__ ei, int E, int N,
                           int* __restrict__ deg, int* __restrict__ adj) {
    int j = blockIdx.x * blockDim.x + threadIdx.x;
    int total = E + N;
    if (j >= total) return;
    int s, d;
    if (j < E) { s = ei[j]; d = ei[E + j]; }     // edge_index[0][j], edge_index[1][j]
    else       { s = j - E; d = s; }             // self loop
    int pos = atomicAdd(&deg[d], 1);
    if (pos < MAXDEG) adj[d * MAXDEG + pos] = s;
}

// ---------------- K2: h1 = x @ W1  [N,256]@[256,32] ---------------------------
__global__ __launch_bounds__(256) void k_gemm1(const float* __restrict__ x,
                                               const float* __restrict__ W1,
                                               float* __restrict__ h1, int N) {
    __shared__ float xs[G1_NODES * FIN];   // 32 KB
    __shared__ float Ws[FIN * F1];         // 32 KB
    int tid = threadIdx.x;
    int node0 = blockIdx.x * G1_NODES;

    const float4* W4 = (const float4*)W1;
    float4* Ws4 = (float4*)Ws;
    for (int i = tid; i < FIN * F1 / 4; i += 256) Ws4[i] = W4[i];

    const float4* x4 = (const float4*)x;
    float4* xs4 = (float4*)xs;
    for (int i = tid; i < G1_NODES * FIN / 4; i += 256) {
        int r = i >> 6;                    // 64 float4 per row
        int n = node0 + r;
        float4 v = make_float4(0.f, 0.f, 0.f, 0.f);
        if (n < N) v = x4[(size_t)n * 64 + (i & 63)];
        xs4[i] = v;
    }
    __syncthreads();

    int ln = tid >> 3;                     // local node 0..31
    int c0 = (tid & 7) * 4;                // output col group
    float a0 = 0.f, a1 = 0.f, a2 = 0.f, a3 = 0.f;
    for (int k = 0; k < FIN; k += 4) {
        float4 xv = *(const float4*)&xs[ln * FIN + k];
        float4 w0 = *(const float4*)&Ws[(k + 0) * F1 + c0];
        float4 w1 = *(const float4*)&Ws[(k + 1) * F1 + c0];
        float4 w2 = *(const float4*)&Ws[(k + 2) * F1 + c0];
        float4 w3 = *(const float4*)&Ws[(k + 3) * F1 + c0];
        a0 += xv.x * w0.x + xv.y * w1.x + xv.z * w2.x + xv.w * w3.x;
        a1 += xv.x * w0.y + xv.y * w1.y + xv.z * w2.y + xv.w * w3.y;
        a2 += xv.x * w0.z + xv.y * w1.z + xv.z * w2.z + xv.w * w3.z;
        a3 += xv.x * w0.w + xv.y * w1.w + xv.z * w2.w + xv.w * w3.w;
    }
    int n = node0 + ln;
    if (n < N) {
        float4 o = make_float4(a0, a1, a2, a3);
        *(float4*)&h1[(size_t)n * F1 + c0] = o;
    }
}

// ---------------- K3: per-node attention dots, layer 1 -------------------------
__global__ void k_attdots1(const float* __restrict__ h1,
                           const float* __restrict__ attS, const float* __restrict__ attD,
                           float* __restrict__ aS, float* __restrict__ aD, int N) {
    int idx = blockIdx.x * blockDim.x + threadIdx.x;
    if (idx >= N * H1) return;
    int n = idx >> 1, h = idx & 1;
    const float* hp = h1 + (size_t)n * F1 + h * C1;
    const float* sp = attS + h * C1;
    const float* dp = attD + h * C1;
    float s = 0.f, d = 0.f;
#pragma unroll
    for (int c = 0; c < C1; c++) { float v = hp[c]; s += v * sp[c]; d += v * dp[c]; }
    aS[idx] = s; aD[idx] = d;
}

// ---------------- K4: layer-1 softmax-aggregate (one wave per node) ------------
// Phase 1: per-edge attention value + softmax weight, kept in registers.
// Phase 2: 8 edge-groups x 8 channel-lanes, float4-coalesced h1 row gathers,
//          weights redistributed via shfl. NOTE: all __shfl must execute
//          full-wave (convergent op; divergent ternary around shfl reads
//          inactive source lanes -> garbage). Shuffle both heads, then select.
__global__ __launch_bounds__(256) void k_agg1(const float* __restrict__ h1,
                                              const int* __restrict__ adj,
                                              const int* __restrict__ deg,
                                              const float* __restrict__ aS,
                                              const float* __restrict__ aD,
                                              const float* __restrict__ b1,
                                              float* __restrict__ h1r, int N) {
    int warp = threadIdx.x >> 6;
    int lane = threadIdx.x & 63;
    int node = blockIdx.x * 4 + warp;
    if (node >= N) return;
    int dg = min(deg[node], MAXDEG);
    float2 adp = *(const float2*)&aD[node * 2];
    const int* ap = adj + (size_t)node * MAXDEG;

    // phase 1: edges lane and lane+64 (dg <= 96 < 128)
    int s0 = 0, s1 = 0;
    float e00 = -INFINITY, e01 = -INFINITY, e10 = -INFINITY, e11 = -INFINITY;
    if (lane < dg) {
        s0 = ap[lane];
        float2 as = *(const float2*)&aS[2 * s0];
        e00 = lrelu(as.x + adp.x); e01 = lrelu(as.y + adp.y);
    }
    if (lane + 64 < dg) {
        s1 = ap[lane + 64];
        float2 as = *(const float2*)&aS[2 * s1];
        e10 = lrelu(as.x + adp.x); e11 = lrelu(as.y + adp.y);
    }
    float m0 = fmaxf(e00, e10), m1 = fmaxf(e01, e11);
#pragma unroll
    for (int off = 32; off; off >>= 1) {
        m0 = fmaxf(m0, __shfl_xor(m0, off));
        m1 = fmaxf(m1, __shfl_xor(m1, off));
    }
    float w00 = (lane < dg)      ? __expf(e00 - m0) : 0.f;
    float w01 = (lane < dg)      ? __expf(e01 - m1) : 0.f;
    float w10 = (lane + 64 < dg) ? __expf(e10 - m0) : 0.f;
    float w11 = (lane + 64 < dg) ? __expf(e11 - m1) : 0.f;
    float sw0 = w00 + w10, sw1 = w01 + w11;
#pragma unroll
    for (int off = 32; off; off >>= 1) {
        sw0 += __shfl_xor(sw0, off);
        sw1 += __shfl_xor(sw1, off);
    }

    // phase 2: 8 edges in flight x 8 lanes x float4 channels
    int eg = lane >> 3;
    int cg = lane & 7;               // channels cg*4 .. cg*4+3
    int head = cg >> 2;              // 0 for ch<16, 1 for ch>=16
    float4 acc = make_float4(0.f, 0.f, 0.f, 0.f);
    for (int j0 = 0; j0 < dg; j0 += 8) {
        int j = j0 + eg;
        int sl = j & 63;
        int s; float w;
        if (j0 < 64) {               // wave-uniform branch: shfls run full-exec
            s = __shfl(s0, sl);
            float wA = __shfl(w00, sl);   // full-wave shuffle of BOTH heads,
            float wB = __shfl(w01, sl);   // then per-lane select (no divergence
            w = head ? wB : wA;           // around the convergent shfl)
        } else {
            s = __shfl(s1, sl);
            float wA = __shfl(w10, sl);
            float wB = __shfl(w11, sl);
            w = head ? wB : wA;
        }
        float4 hv = *(const float4*)&h1[(size_t)s * F1 + cg * 4];
        acc.x += w * hv.x; acc.y += w * hv.y; acc.z += w * hv.z; acc.w += w * hv.w;
    }
#pragma unroll
    for (int off = 8; off < 64; off <<= 1) {
        acc.x += __shfl_xor(acc.x, off);
        acc.y += __shfl_xor(acc.y, off);
        acc.z += __shfl_xor(acc.z, off);
        acc.w += __shfl_xor(acc.w, off);
    }
    if (eg == 0) {
        float swh = head ? sw1 : sw0;
        float inv = 1.f / (swh + GAT_EPS);
        float4 bv = *(const float4*)&b1[cg * 4];
        float4 o;
        o.x = fmaxf(acc.x * inv + bv.x, 0.f);
        o.y = fmaxf(acc.y * inv + bv.y, 0.f);
        o.z = fmaxf(acc.z * inv + bv.z, 0.f);
        o.w = fmaxf(acc.w * inv + bv.w, 0.f);
        *(float4*)&h1r[(size_t)node * F1 + cg * 4] = o;
    }
}

// ---------------- K5: h2 = h1r @ W2  [N,32]@[32,40] ---------------------------
__global__ __launch_bounds__(320) void k_gemm2(const float* __restrict__ h1r,
                                               const float* __restrict__ W2,
                                               float* __restrict__ h2, int N) {
    __shared__ float hs[8 * F1];       // 1 KB
    __shared__ float Ws[F1 * C2];      // 5 KB
    int tid = threadIdx.x;
    int node0 = blockIdx.x * 8;
    for (int i = tid; i < F1 * C2; i += 320) Ws[i] = W2[i];
    if (tid < 8 * F1) {
        int r = tid >> 5;
        int n = node0 + r;
        hs[tid] = (n < N) ? h1r[(size_t)n * F1 + (tid & 31)] : 0.f;
    }
    __syncthreads();
    int node = tid / C2;
    int col  = tid - node * C2;        // 320 = 8 * 40 exactly
    int n = node0 + node;
    if (n < N) {
        float acc = 0.f;
#pragma unroll
        for (int k = 0; k < F1; k++) acc += hs[node * F1 + k] * Ws[k * C2 + col];
        h2[(size_t)n * C2 + col] = acc;
    }
}

// ---------------- K6: per-node attention dots, layer 2 -------------------------
__global__ void k_attdots2(const float* __restrict__ h2,
                           const float* __restrict__ attS, const float* __restrict__ attD,
                           float* __restrict__ aS, float* __restrict__ aD, int N) {
    int n = blockIdx.x * blockDim.x + threadIdx.x;
    if (n >= N) return;
    const float* hp = h2 + (size_t)n * C2;
    float s = 0.f, d = 0.f;
#pragma unroll
    for (int c = 0; c < C2; c++) { float v = hp[c]; s += v * attS[c]; d += v * attD[c]; }
    aS[n] = s; aD[n] = d;
}

// ---------------- K7: layer-2 aggregate + bias + log_softmax -------------------
// Same 8x8 structure. All shfls run under wave-uniform control flow.
__global__ __launch_bounds__(256) void k_agg2(const float* __restrict__ h2,
                                              const int* __restrict__ adj,
                                              const int* __restrict__ deg,
                                              const float* __restrict__ aS,
                                              const float* __restrict__ aD,
                                              const float* __restrict__ b2,
                                              float* __restrict__ out, int N) {
    int warp = threadIdx.x >> 6;
    int lane = threadIdx.x & 63;
    int node = blockIdx.x * 4 + warp;
    if (node >= N) return;
    int dg = min(deg[node], MAXDEG);
    float ad = aD[node];
    const int* ap = adj + (size_t)node * MAXDEG;

    // phase 1
    int s0 = 0, s1 = 0;
    float e0 = -INFINITY, e1 = -INFINITY;
    if (lane < dg)      { s0 = ap[lane];      e0 = lrelu(aS[s0] + ad); }
    if (lane + 64 < dg) { s1 = ap[lane + 64]; e1 = lrelu(aS[s1] + ad); }
    float m = fmaxf(e0, e1);
#pragma unroll
    for (int off = 32; off; off >>= 1) m = fmaxf(m, __shfl_xor(m, off));
    float w0 = (lane < dg)      ? __expf(e0 - m) : 0.f;
    float w1 = (lane + 64 < dg) ? __expf(e1 - m) : 0.f;
    float sw = w0 + w1;
#pragma unroll
    for (int off = 32; off; off >>= 1) sw += __shfl_xor(sw, off);

    // phase 2: 8 edges x 8 lanes; lane cg -> channels {cg*4..+3, 32+cg}
    int eg = lane >> 3;
    int cg = lane & 7;
    float4 acc = make_float4(0.f, 0.f, 0.f, 0.f);
    float acc4 = 0.f;
    for (int j0 = 0; j0 < dg; j0 += 8) {
        int j = j0 + eg;
        int sl = j & 63;
        int s; float w;
        if (j0 < 64) { s = __shfl(s0, sl); w = __shfl(w0, sl); }
        else         { s = __shfl(s1, sl); w = __shfl(w1, sl); }
        const float* hp = &h2[(size_t)s * C2];
        float4 hv = *(const float4*)&hp[cg * 4];
        float  h5 = hp[32 + cg];
        acc.x += w * hv.x; acc.y += w * hv.y; acc.z += w * hv.z; acc.w += w * hv.w;
        acc4  += w * h5;
    }
#pragma unroll
    for (int off = 8; off < 64; off <<= 1) {
        acc.x += __shfl_xor(acc.x, off);
        acc.y += __shfl_xor(acc.y, off);
        acc.z += __shfl_xor(acc.z, off);
        acc.w += __shfl_xor(acc.w, off);
        acc4  += __shfl_xor(acc4, off);
    }
    // every lane now holds its cg's totals; compute on all, store from eg==0
    float inv = 1.f / (sw + GAT_EPS);
    float4 bv = *(const float4*)&b2[cg * 4];
    float  b5 = b2[32 + cg];
    float v0 = acc.x * inv + bv.x;
    float v1 = acc.y * inv + bv.y;
    float v2 = acc.z * inv + bv.z;
    float v3 = acc.w * inv + bv.w;
    float v4 = acc4  * inv + b5;

    // log_softmax across the 40 values (5 per lane x 8 cg lanes, xor 1/2/4)
    float lm = fmaxf(fmaxf(fmaxf(v0, v1), fmaxf(v2, v3)), v4);
#pragma unroll
    for (int off = 1; off < 8; off <<= 1) lm = fmaxf(lm, __shfl_xor(lm, off));
    float ex = __expf(v0 - lm) + __expf(v1 - lm) + __expf(v2 - lm) +
               __expf(v3 - lm) + __expf(v4 - lm);
#pragma unroll
    for (int off = 1; off < 8; off <<= 1) ex += __shfl_xor(ex, off);
    float lse = lm + __logf(ex);
    if (eg == 0) {
        float* op = out + (size_t)node * C2;
        float4 o = make_float4(v0 - lse, v1 - lse, v2 - lse, v3 - lse);
        *(float4*)&op[cg * 4] = o;
        op[32 + cg] = v4 - lse;
    }
}

extern "C" void kernel_launch(void* const* d_in, const int* in_sizes, int n_in,
                              void* d_out, int out_size, void* d_ws, size_t ws_size,
                              hipStream_t stream) {
    const float* x    = (const float*)d_in[0];
    const int*   ei   = (const int*)d_in[1];
    const float* W1   = (const float*)d_in[2];
    const float* aS1w = (const float*)d_in[3];
    const float* aD1w = (const float*)d_in[4];
    const float* b1   = (const float*)d_in[5];
    const float* W2   = (const float*)d_in[6];
    const float* aS2w = (const float*)d_in[7];
    const float* aD2w = (const float*)d_in[8];
    const float* b2   = (const float*)d_in[9];
    const int N = in_sizes[0] / FIN;
    const int E = in_sizes[1] / 2;

    char* ws = (char*)d_ws;
    size_t off = 0;
    auto alloc = [&](size_t bytes) -> void* {
        void* p = ws + off;
        off = (off + bytes + 511) & ~(size_t)511;
        return p;
    };
    int*   deg = (int*)alloc(sizeof(int) * (size_t)N);
    int*   adj = (int*)alloc(sizeof(int) * (size_t)N * MAXDEG);
    float* h1  = (float*)alloc(sizeof(float) * (size_t)N * F1);
    float* aS1 = (float*)alloc(sizeof(float) * (size_t)N * H1);
    float* aD1 = (float*)alloc(sizeof(float) * (size_t)N * H1);
    float* h1r = (float*)alloc(sizeof(float) * (size_t)N * F1);
    float* h2  = (float*)alloc(sizeof(float) * (size_t)N * C2);
    float* aS2 = (float*)alloc(sizeof(float) * (size_t)N);
    float* aD2 = (float*)alloc(sizeof(float) * (size_t)N);

    hipMemsetAsync(deg, 0, sizeof(int) * (size_t)N, stream);
    int total = E + N;
    k_fill_adj<<<(total + 255) / 256, 256, 0, stream>>>(ei, E, N, deg, adj);
    k_gemm1<<<(N + G1_NODES - 1) / G1_NODES, 256, 0, stream>>>(x, W1, h1, N);
    k_attdots1<<<(N * H1 + 255) / 256, 256, 0, stream>>>(h1, aS1w, aD1w, aS1, aD1, N);
    k_agg1<<<(N + 3) / 4, 256, 0, stream>>>(h1, adj, deg, aS1, aD1, b1, h1r, N);
    k_gemm2<<<(N + 7) / 8, 320, 0, stream>>>(h1r, W2, h2, N);
    k_attdots2<<<(N + 255) / 256, 256, 0, stream>>>(h2, aS2w, aD2w, aS2, aD2, N);
    k_agg2<<<(N + 3) / 4, 256, 0, stream>>>(h2, adj, deg, aS2, aD2, b2, (float*)d_out, N);
}

// Round 4
// 574.528 us; speedup vs baseline: 1.7697x; 1.0362x over previous
//
#include <hip/hip_runtime.h>
#include <math.h>

#define FIN 256      // input features
#define F1  32       // heads1 * C1
#define H1  2
#define C1  16
#define C2  40       // layer-2 out channels (= num classes)
#define MAXDEG 96    // padded adjacency capacity (Poisson(32) tail ~1e-18/node)
#define NEG_SLOPE 0.2f
#define GAT_EPS 1e-16f
#define G1_NODES 32  // nodes per block in GEMM1
#define FILL_BLOCKS 2048   // 8 blocks/CU on 256 CUs; blockIdx&7 ~ XCD (heuristic)

__device__ __forceinline__ float lrelu(float v) { return v >= 0.f ? v : NEG_SLOPE * v; }

// ---------------- K1: build padded adjacency, XCD-binned by dst range ----------
// Each residue class (blockIdx&7 -> one XCD under round-robin dispatch) scans
// the WHOLE edge list (nontemporal: zero reuse within an XCD) but scatters only
// dst in its 1/8 node range -> adj slice ~4.8MB stays L2-resident, so the ~5.5
// writes landing on each 64B line coalesce before one eviction (was: 196MB of
// single-entry line writes). Correct regardless of actual block->XCD mapping.
__global__ __launch_bounds__(256) void k_fill_adj(const int* __restrict__ ei, int E, int N,
                                                  int* __restrict__ deg, int* __restrict__ adj) {
    int res = blockIdx.x & 7;
    int nper = (N + 7) >> 3;
    int lo = res * nper;
    int hi = min(N, lo + nper);
    int total = E + N;
    int stride = (gridDim.x >> 3) * blockDim.x;
    for (int j = (blockIdx.x >> 3) * blockDim.x + threadIdx.x; j < total; j += stride) {
        int d, s;
        if (j < E) {
            d = __builtin_nontemporal_load(&ei[E + j]);
            s = 0;
            if (d >= lo && d < hi) s = __builtin_nontemporal_load(&ei[j]);
        } else {
            d = j - E; s = d;                      // self loop
        }
        if (d >= lo && d < hi) {
            int pos = atomicAdd(&deg[d], 1);
            if (pos < MAXDEG) adj[d * MAXDEG + pos] = s;
        }
    }
}

// ---------------- K2: h1 = x @ W1  [N,256]@[256,32]  + fused att dots ---------
__global__ __launch_bounds__(256) void k_gemm1(const float* __restrict__ x,
                                               const float* __restrict__ W1,
                                               const float* __restrict__ attS,
                                               const float* __restrict__ attD,
                                               float* __restrict__ h1,
                                               float* __restrict__ aS,
                                               float* __restrict__ aD, int N) {
    __shared__ float xs[G1_NODES * FIN];   // 32 KB
    __shared__ float Ws[FIN * F1];         // 32 KB
    int tid = threadIdx.x;
    int node0 = blockIdx.x * G1_NODES;

    const float4* W4 = (const float4*)W1;
    float4* Ws4 = (float4*)Ws;
    for (int i = tid; i < FIN * F1 / 4; i += 256) Ws4[i] = W4[i];

    const float4* x4 = (const float4*)x;
    float4* xs4 = (float4*)xs;
    for (int i = tid; i < G1_NODES * FIN / 4; i += 256) {
        int r = i >> 6;                    // 64 float4 per row
        int n = node0 + r;
        float4 v = make_float4(0.f, 0.f, 0.f, 0.f);
        if (n < N) v = x4[(size_t)n * 64 + (i & 63)];
        xs4[i] = v;
    }
    __syncthreads();

    int ln = tid >> 3;                     // local node 0..31
    int c0 = (tid & 7) * 4;                // output col group
    float a0 = 0.f, a1 = 0.f, a2 = 0.f, a3 = 0.f;
    for (int k = 0; k < FIN; k += 4) {
        float4 xv = *(const float4*)&xs[ln * FIN + k];
        float4 w0 = *(const float4*)&Ws[(k + 0) * F1 + c0];
        float4 w1 = *(const float4*)&Ws[(k + 1) * F1 + c0];
        float4 w2 = *(const float4*)&Ws[(k + 2) * F1 + c0];
        float4 w3 = *(const float4*)&Ws[(k + 3) * F1 + c0];
        a0 += xv.x * w0.x + xv.y * w1.x + xv.z * w2.x + xv.w * w3.x;
        a1 += xv.x * w0.y + xv.y * w1.y + xv.z * w2.y + xv.w * w3.y;
        a2 += xv.x * w0.z + xv.y * w1.z + xv.z * w2.z + xv.w * w3.z;
        a3 += xv.x * w0.w + xv.y * w1.w + xv.z * w2.w + xv.w * w3.w;
    }

    // fused attention dots: 8 consecutive lanes own one node's 32 channels.
    // attS/attD flattened [32]; head0 = ch 0..15 (tid&7 in 0..3), head1 = 16..31.
    // All shuffles full-wave (before any divergent guard).
    float4 sv = *(const float4*)&attS[c0];
    float4 dv = *(const float4*)&attD[c0];
    float ps = a0 * sv.x + a1 * sv.y + a2 * sv.z + a3 * sv.w;
    float pd = a0 * dv.x + a1 * dv.y + a2 * dv.z + a3 * dv.w;
    ps += __shfl_xor(ps, 1); ps += __shfl_xor(ps, 2);
    pd += __shfl_xor(pd, 1); pd += __shfl_xor(pd, 2);
    float po = __shfl_xor(ps, 4);          // other head's S-dot
    float qo = __shfl_xor(pd, 4);          // other head's D-dot

    int n = node0 + ln;
    if (n < N) {
        *(float4*)&h1[(size_t)n * F1 + c0] = make_float4(a0, a1, a2, a3);
        if ((tid & 7) == 0) {              // lane holds (head0, head1) = (ps, po)
            *(float2*)&aS[2 * (size_t)n] = make_float2(ps, po);
            *(float2*)&aD[2 * (size_t)n] = make_float2(pd, qo);
        }
    }
}

// ---------------- K4: layer-1 softmax-aggregate (one wave per node) ------------
__global__ __launch_bounds__(256) void k_agg1(const float* __restrict__ h1,
                                              const int* __restrict__ adj,
                                              const int* __restrict__ deg,
                                              const float* __restrict__ aS,
                                              const float* __restrict__ aD,
                                              const float* __restrict__ b1,
                                              float* __restrict__ h1r, int N) {
    int warp = threadIdx.x >> 6;
    int lane = threadIdx.x & 63;
    int node = blockIdx.x * 4 + warp;
    if (node >= N) return;
    int dg = min(deg[node], MAXDEG);
    float2 adp = *(const float2*)&aD[node * 2];
    const int* ap = adj + (size_t)node * MAXDEG;

    // phase 1: edges lane and lane+64 (dg <= 96 < 128)
    int s0 = 0, s1 = 0;
    float e00 = -INFINITY, e01 = -INFINITY, e10 = -INFINITY, e11 = -INFINITY;
    if (lane < dg) {
        s0 = ap[lane];
        float2 as = *(const float2*)&aS[2 * s0];
        e00 = lrelu(as.x + adp.x); e01 = lrelu(as.y + adp.y);
    }
    if (lane + 64 < dg) {
        s1 = ap[lane + 64];
        float2 as = *(const float2*)&aS[2 * s1];
        e10 = lrelu(as.x + adp.x); e11 = lrelu(as.y + adp.y);
    }
    float m0 = fmaxf(e00, e10), m1 = fmaxf(e01, e11);
#pragma unroll
    for (int off = 32; off; off >>= 1) {
        m0 = fmaxf(m0, __shfl_xor(m0, off));
        m1 = fmaxf(m1, __shfl_xor(m1, off));
    }
    float w00 = (lane < dg)      ? __expf(e00 - m0) : 0.f;
    float w01 = (lane < dg)      ? __expf(e01 - m1) : 0.f;
    float w10 = (lane + 64 < dg) ? __expf(e10 - m0) : 0.f;
    float w11 = (lane + 64 < dg) ? __expf(e11 - m1) : 0.f;
    float sw0 = w00 + w10, sw1 = w01 + w11;
#pragma unroll
    for (int off = 32; off; off >>= 1) {
        sw0 += __shfl_xor(sw0, off);
        sw1 += __shfl_xor(sw1, off);
    }

    // phase 2: 8 edges in flight x 8 lanes x float4 channels
    int eg = lane >> 3;
    int cg = lane & 7;               // channels cg*4 .. cg*4+3
    int head = cg >> 2;              // 0 for ch<16, 1 for ch>=16
    float4 acc = make_float4(0.f, 0.f, 0.f, 0.f);
    for (int j0 = 0; j0 < dg; j0 += 8) {
        int j = j0 + eg;
        int sl = j & 63;
        int s; float w;
        if (j0 < 64) {               // wave-uniform branch: shfls run full-exec
            s = __shfl(s0, sl);
            float wA = __shfl(w00, sl);
            float wB = __shfl(w01, sl);
            w = head ? wB : wA;
        } else {
            s = __shfl(s1, sl);
            float wA = __shfl(w10, sl);
            float wB = __shfl(w11, sl);
            w = head ? wB : wA;
        }
        float4 hv = *(const float4*)&h1[(size_t)s * F1 + cg * 4];
        acc.x += w * hv.x; acc.y += w * hv.y; acc.z += w * hv.z; acc.w += w * hv.w;
    }
#pragma unroll
    for (int off = 8; off < 64; off <<= 1) {
        acc.x += __shfl_xor(acc.x, off);
        acc.y += __shfl_xor(acc.y, off);
        acc.z += __shfl_xor(acc.z, off);
        acc.w += __shfl_xor(acc.w, off);
    }
    if (eg == 0) {
        float swh = head ? sw1 : sw0;
        float inv = 1.f / (swh + GAT_EPS);
        float4 bv = *(const float4*)&b1[cg * 4];
        float4 o;
        o.x = fmaxf(acc.x * inv + bv.x, 0.f);
        o.y = fmaxf(acc.y * inv + bv.y, 0.f);
        o.z = fmaxf(acc.z * inv + bv.z, 0.f);
        o.w = fmaxf(acc.w * inv + bv.w, 0.f);
        *(float4*)&h1r[(size_t)node * F1 + cg * 4] = o;
    }
}

// ---------------- K5: h2 = h1r @ W2  [N,32]@[32,40] ---------------------------
__global__ __launch_bounds__(320) void k_gemm2(const float* __restrict__ h1r,
                                               const float* __restrict__ W2,
                                               float* __restrict__ h2, int N) {
    __shared__ float hs[8 * F1];       // 1 KB
    __shared__ float Ws[F1 * C2];      // 5 KB
    int tid = threadIdx.x;
    int node0 = blockIdx.x * 8;
    for (int i = tid; i < F1 * C2; i += 320) Ws[i] = W2[i];
    if (tid < 8 * F1) {
        int r = tid >> 5;
        int n = node0 + r;
        hs[tid] = (n < N) ? h1r[(size_t)n * F1 + (tid & 31)] : 0.f;
    }
    __syncthreads();
    int node = tid / C2;
    int col  = tid - node * C2;        // 320 = 8 * 40 exactly
    int n = node0 + node;
    if (n < N) {
        float acc = 0.f;
#pragma unroll
        for (int k = 0; k < F1; k++) acc += hs[node * F1 + k] * Ws[k * C2 + col];
        h2[(size_t)n * C2 + col] = acc;
    }
}

// ---------------- K6: per-node attention dots, layer 2 -------------------------
__global__ void k_attdots2(const float* __restrict__ h2,
                           const float* __restrict__ attS, const float* __restrict__ attD,
                           float* __restrict__ aS, float* __restrict__ aD, int N) {
    int n = blockIdx.x * blockDim.x + threadIdx.x;
    if (n >= N) return;
    const float* hp = h2 + (size_t)n * C2;
    float s = 0.f, d = 0.f;
#pragma unroll
    for (int c = 0; c < C2; c++) { float v = hp[c]; s += v * attS[c]; d += v * attD[c]; }
    aS[n] = s; aD[n] = d;
}

// ---------------- K7: layer-2 aggregate + bias + log_softmax -------------------
__global__ __launch_bounds__(256) void k_agg2(const float* __restrict__ h2,
                                              const int* __restrict__ adj,
                                              const int* __restrict__ deg,
                                              const float* __restrict__ aS,
                                              const float* __restrict__ aD,
                                              const float* __restrict__ b2,
                                              float* __restrict__ out, int N) {
    int warp = threadIdx.x >> 6;
    int lane = threadIdx.x & 63;
    int node = blockIdx.x * 4 + warp;
    if (node >= N) return;
    int dg = min(deg[node], MAXDEG);
    float ad = aD[node];
    const int* ap = adj + (size_t)node * MAXDEG;

    // phase 1
    int s0 = 0, s1 = 0;
    float e0 = -INFINITY, e1 = -INFINITY;
    if (lane < dg)      { s0 = ap[lane];      e0 = lrelu(aS[s0] + ad); }
    if (lane + 64 < dg) { s1 = ap[lane + 64]; e1 = lrelu(aS[s1] + ad); }
    float m = fmaxf(e0, e1);
#pragma unroll
    for (int off = 32; off; off >>= 1) m = fmaxf(m, __shfl_xor(m, off));
    float w0 = (lane < dg)      ? __expf(e0 - m) : 0.f;
    float w1 = (lane + 64 < dg) ? __expf(e1 - m) : 0.f;
    float sw = w0 + w1;
#pragma unroll
    for (int off = 32; off; off >>= 1) sw += __shfl_xor(sw, off);

    // phase 2: 8 edges x 8 lanes; lane cg -> channels {cg*4..+3, 32+cg}
    int eg = lane >> 3;
    int cg = lane & 7;
    float4 acc = make_float4(0.f, 0.f, 0.f, 0.f);
    float acc4 = 0.f;
    for (int j0 = 0; j0 < dg; j0 += 8) {
        int j = j0 + eg;
        int sl = j & 63;
        int s; float w;
        if (j0 < 64) { s = __shfl(s0, sl); w = __shfl(w0, sl); }
        else         { s = __shfl(s1, sl); w = __shfl(w1, sl); }
        const float* hp = &h2[(size_t)s * C2];
        float4 hv = *(const float4*)&hp[cg * 4];
        float  h5 = hp[32 + cg];
        acc.x += w * hv.x; acc.y += w * hv.y; acc.z += w * hv.z; acc.w += w * hv.w;
        acc4  += w * h5;
    }
#pragma unroll
    for (int off = 8; off < 64; off <<= 1) {
        acc.x += __shfl_xor(acc.x, off);
        acc.y += __shfl_xor(acc.y, off);
        acc.z += __shfl_xor(acc.z, off);
        acc.w += __shfl_xor(acc.w, off);
        acc4  += __shfl_xor(acc4, off);
    }
    float inv = 1.f / (sw + GAT_EPS);
    float4 bv = *(const float4*)&b2[cg * 4];
    float  b5 = b2[32 + cg];
    float v0 = acc.x * inv + bv.x;
    float v1 = acc.y * inv + bv.y;
    float v2 = acc.z * inv + bv.z;
    float v3 = acc.w * inv + bv.w;
    float v4 = acc4  * inv + b5;

    // log_softmax across the 40 values (5 per lane x 8 cg lanes, xor 1/2/4)
    float lm = fmaxf(fmaxf(fmaxf(v0, v1), fmaxf(v2, v3)), v4);
#pragma unroll
    for (int off = 1; off < 8; off <<= 1) lm = fmaxf(lm, __shfl_xor(lm, off));
    float ex = __expf(v0 - lm) + __expf(v1 - lm) + __expf(v2 - lm) +
               __expf(v3 - lm) + __expf(v4 - lm);
#pragma unroll
    for (int off = 1; off < 8; off <<= 1) ex += __shfl_xor(ex, off);
    float lse = lm + __logf(ex);
    if (eg == 0) {
        float* op = out + (size_t)node * C2;
        float4 o = make_float4(v0 - lse, v1 - lse, v2 - lse, v3 - lse);
        *(float4*)&op[cg * 4] = o;
        op[32 + cg] = v4 - lse;
    }
}

extern "C" void kernel_launch(void* const* d_in, const int* in_sizes, int n_in,
                              void* d_out, int out_size, void* d_ws, size_t ws_size,
                              hipStream_t stream) {
    const float* x    = (const float*)d_in[0];
    const int*   ei   = (const int*)d_in[1];
    const float* W1   = (const float*)d_in[2];
    const float* aS1w = (const float*)d_in[3];
    const float* aD1w = (const float*)d_in[4];
    const float* b1   = (const float*)d_in[5];
    const float* W2   = (const float*)d_in[6];
    const float* aS2w = (const float*)d_in[7];
    const float* aD2w = (const float*)d_in[8];
    const float* b2   = (const float*)d_in[9];
    const int N = in_sizes[0] / FIN;
    const int E = in_sizes[1] / 2;

    char* ws = (char*)d_ws;
    size_t off = 0;
    auto alloc = [&](size_t bytes) -> void* {
        void* p = ws + off;
        off = (off + bytes + 511) & ~(size_t)511;
        return p;
    };
    int*   deg = (int*)alloc(sizeof(int) * (size_t)N);
    int*   adj = (int*)alloc(sizeof(int) * (size_t)N * MAXDEG);
    float* h1  = (float*)alloc(sizeof(float) * (size_t)N * F1);
    float* aS1 = (float*)alloc(sizeof(float) * (size_t)N * H1);
    float* aD1 = (float*)alloc(sizeof(float) * (size_t)N * H1);
    float* h1r = (float*)alloc(sizeof(float) * (size_t)N * F1);
    float* h2  = (float*)alloc(sizeof(float) * (size_t)N * C2);
    float* aS2 = (float*)alloc(sizeof(float) * (size_t)N);
    float* aD2 = (float*)alloc(sizeof(float) * (size_t)N);

    hipMemsetAsync(deg, 0, sizeof(int) * (size_t)N, stream);
    k_fill_adj<<<FILL_BLOCKS, 256, 0, stream>>>(ei, E, N, deg, adj);
    k_gemm1<<<(N + G1_NODES - 1) / G1_NODES, 256, 0, stream>>>(x, W1, aS1w, aD1w, h1, aS1, aD1, N);
    k_agg1<<<(N + 3) / 4, 256, 0, stream>>>(h1, adj, deg, aS1, aD1, b1, h1r, N);
    k_gemm2<<<(N + 7) / 8, 320, 0, stream>>>(h1r, W2, h2, N);
    k_attdots2<<<(N + 255) / 256, 256, 0, stream>>>(h2, aS2w, aD2w, aS2, aD2, N);
    k_agg2<<<(N + 3) / 4, 256, 0, stream>>>(h2, adj, deg, aS2, aD2, b2, (float*)d_out, N);
}